// Round 11
// baseline (427.466 us; speedup 1.0000x reference)
//
#include <hip/hip_runtime.h>
#include <hip/hip_bf16.h>

typedef __hip_bfloat16 bf16;

#define HW 128
#define IMG 16384     // 128*128
#define EPSV 1e-5f

typedef __bf16 b16x8 __attribute__((ext_vector_type(8)));
typedef float f32x16 __attribute__((ext_vector_type(16)));

__device__ __forceinline__ float u2f(unsigned int u){ union{unsigned int i; float f;}c; c.i=u; return c.f; }
__device__ __forceinline__ float blo(unsigned int u){ return u2f(u<<16); }
__device__ __forceinline__ float bhi(unsigned int u){ return u2f(u & 0xffff0000u); }
__device__ __forceinline__ unsigned short f2bu(float v){ bf16 h=__float2bfloat16(v); union{bf16 b; unsigned short s;}c; c.b=h; return c.s; }
__device__ __forceinline__ unsigned int pk(float a, float b){ return (unsigned int)f2bu(a) | ((unsigned int)f2bu(b)<<16); }
__device__ __forceinline__ bf16 f2b(float v){ return __float2bfloat16(v); }
__device__ __forceinline__ float sigm(float x){ return 1.f/(1.f+__expf(-x)); }

__device__ __forceinline__ void gload16(const void* g, void* l) {
    __builtin_amdgcn_global_load_lds((const __attribute__((address_space(1))) unsigned int*)(g),
                                     (__attribute__((address_space(3))) unsigned int*)(l), 16, 0, 0);
}

__device__ __forceinline__ f32x16 MFMA(b16x8 a, b16x8 b, f32x16 c){
    return __builtin_amdgcn_mfma_f32_32x32x16_bf16(a, b, c, 0, 0, 0);
}

// ---------------------------------------------------------------------------
// MFMA implicit-GEMM 3x3 conv, SAME padding — 8-wave high-occupancy (R10)
// + optional INPUT GroupNorm+SiLU applied IN-LDS after raw staging (GNIN).
// Block 512 thr (8 waves): wave = 2 M-frags x 2 N-frags (64px x 64co),
// acc = 64 regs -> 4 waves/SIMD. Grid (64,1,8); tile = 2 rows x 128 px x COUT.
// X slab (2 rows + halo, 64 cin) staged RAW via global_load_lds (swizzled
// source); if GNIN, an in-LDS pass applies per-(n,cin) affine+SiLU to valid
// chunks (halo stays exact zero), one extra barrier per slab.
// W slice [COUT][64cin] double-buffered, staged during MFMA of prev phase.
// TADD: add constant-channel table Tt[n][co][3][3] (c1).
// FUSE_GN: emit per-(n,tile) GN partials of RAW output (8 grp x {sum,sumsq}).
// FUSE_XT: out = silu(affine(featA;fsc,fbi)) - alpha*conv; wg-pool partials.
// ---------------------------------------------------------------------------
template<int CIN, int COUT, bool TADD, bool GNIN, bool FUSE_GN, bool FUSE_XT>
__global__ void __launch_bounds__(512, 4)
mfma_conv3x3(const bf16* __restrict__ act,
             const bf16* __restrict__ Wt,
             const float* __restrict__ Bt,
             bf16* __restrict__ outp,
             const float* __restrict__ Tt,
             const bf16* __restrict__ zerobuf,
             float* __restrict__ gpart,
             const float* __restrict__ gnin_sc,
             const float* __restrict__ gnin_bi,
             const bf16* __restrict__ featA,
             const float* __restrict__ fsc,
             const float* __restrict__ fbi,
             const int* __restrict__ tsel,
             const float* __restrict__ wgw,
             float* __restrict__ wpart)
{
    static_assert(CIN==64 || CIN==128, "");
    static_assert(COUT==64 || COUT==128, "");
    constexpr int NQ  = COUT/64;      // n-frags per wave (co-half has NQ*32 co)
    constexpr int CH  = CIN/64;       // cin chunks
    constexpr int P   = 9*CH;         // phases
    constexpr int WCH = COUT/8;       // weight chunks (1KB each)
    constexpr int WSZ = WCH*1024;

    __shared__ char Xb[33792];        // 264 slots x 128B (260 used: 2 rows x 130 x')
    __shared__ char Wa[2][WSZ];
    __shared__ float redS[8][4], redSS[8][4], redW[8];

    const int n    = blockIdx.z;
    const int tile = blockIdx.x;
    const int y0   = tile*2;
    const int tid  = threadIdx.x;
    const int lane = tid & 63;
    const int wid  = tid >> 6;        // 0..7
    const int row  = wid >> 2;        // image row within tile (0/1)
    const int coh  = (wid >> 1) & 1;  // co half
    const int pxh  = wid & 1;         // px half (x offset 0 / 64)
    const int l31  = lane & 31;
    const int lhi  = lane >> 5;
    const int g    = lane & 7;

    const bf16* actN = act + (size_t)n * IMG * CIN;
    const bf16* WtN  = Wt  + (size_t)n * 9 * COUT * CIN;

    f32x16 acc[2][NQ];
    #pragma unroll
    for (int i=0;i<2;++i)
        #pragma unroll
        for (int j=0;j<NQ;++j)
            #pragma unroll
            for (int k=0;k<16;++k) acc[i][j][k] = 0.f;

    // ---- raw X slab staging (rows y0+dy-1..y0+dy, 64 cin; swizzled src) ----
    auto stage_X = [&](int dy, int ch) {
        const int ry0 = y0 + dy - 1;
        for (int u = wid; u < 33; u += 8) {
            int s = u*8 + (lane>>3);         // slot index
            int r  = (s >= 130) ? 1 : 0;
            int xp = s - r*130;
            int xx = xp - 1;
            int ry = ry0 + r;
            const void* src = zerobuf;
            if (s < 260 && (unsigned)xx < 128u && (unsigned)ry < 128u)
                src = actN + ((size_t)(ry*128 + xx)*CIN + ch*64 + 8*(g ^ (s&7)));
            gload16(src, Xb + u*1024);
        }
    };
    // ---- in-LDS GN+SiLU transform of a staged slab (valid chunks only) ----
    auto transform_X = [&](int dy, int ch) {
        const int ry0 = y0 + dy - 1;
        for (int u = wid; u < 33; u += 8) {
            int s = u*8 + (lane>>3);
            int r  = (s >= 130) ? 1 : 0;
            int xx = s - r*130 - 1;
            int ry = ry0 + r;
            if (!(s < 260 && (unsigned)xx < 128u && (unsigned)ry < 128u)) continue;
            int cc = g ^ (s & 7);            // cin chunk stored at this position
            const float* sp = gnin_sc + n*CIN + ch*64 + cc*8;
            const float* bp = gnin_bi + n*CIN + ch*64 + cc*8;
            uint4* p = (uint4*)(Xb + s*128 + g*16);
            uint4 v = *p;
            float f[8] = {blo(v.x),bhi(v.x),blo(v.y),bhi(v.y),
                          blo(v.z),bhi(v.z),blo(v.w),bhi(v.w)};
            #pragma unroll
            for (int j=0;j<8;++j) { float y = f[j]*sp[j] + bp[j]; f[j] = y*sigm(y); }
            v.x = pk(f[0],f[1]); v.y = pk(f[2],f[3]);
            v.z = pk(f[4],f[5]); v.w = pk(f[6],f[7]);
            *p = v;
        }
    };
    auto stage_W = [&](int r, int ch, int buf) {
        for (int u = wid; u < WCH; u += 8) {
            int co = u*8 + (lane>>3);
            const void* src = WtN + ((size_t)(r*COUT + co)*CIN + ch*64 + 8*(g ^ (co&7)));
            gload16(src, Wa[buf] + u*1024);
        }
    };

    // ---- prologue ----
    stage_X(0, 0);
    stage_W(0, 0, 0);
    __syncthreads();
    if (GNIN) {
        transform_X(0, 0);
        __syncthreads();
    }

    int buf = 0;
    for (int p = 0; p < P; ++p) {
        const int dx = p % 3;
        const bool last = (p+1 == P);

        if (!last) {
            const int pn  = p + 1;
            const int ndx = pn % 3;
            const int npc = pn / 3;
            stage_W((npc/CH)*3 + ndx, npc % CH, buf ^ 1);
        }

        __builtin_amdgcn_s_setprio(1);
        #pragma unroll
        for (int s4 = 0; s4 < 4; ++s4) {
            const int koff = s4*32 + lhi*16;
            b16x8 bfr[NQ];
            #pragma unroll
            for (int q = 0; q < NQ; ++q) {
                int co = coh*32*NQ + q*32 + l31;
                bfr[q] = *(const b16x8*)(Wa[buf] + co*128 + (koff ^ ((co&7)<<4)));
            }
            b16x8 afr[2];
            #pragma unroll
            for (int mt = 0; mt < 2; ++mt) {
                int sl = row*130 + (pxh*2+mt)*32 + l31 + dx;
                afr[mt] = *(const b16x8*)(Xb + sl*128 + (koff ^ ((sl&7)<<4)));
            }
            #pragma unroll
            for (int mt = 0; mt < 2; ++mt)
                #pragma unroll
                for (int q = 0; q < NQ; ++q)
                    acc[mt][q] = MFMA(afr[mt], bfr[q], acc[mt][q]);
        }
        __builtin_amdgcn_s_setprio(0);

        if (!last) {
            if (dx == 2) {
                __syncthreads();
                const int npc = (p + 1) / 3;
                stage_X(npc / CH, npc % CH);
                __syncthreads();
                if (GNIN) {
                    transform_X(npc / CH, npc % CH);
                    __syncthreads();
                }
            } else {
                __syncthreads();
            }
        }
        buf ^= 1;
    }

    // ---- epilogue ----
    const float* BtN = Bt + n*COUT;
    const int y = y0 + row;
    bf16* outRow = outp + ((size_t)n*IMG + (size_t)y*128)*COUT;
    const bf16* featRow = FUSE_XT ? (featA + ((size_t)n*IMG + (size_t)y*128)*COUT) : nullptr;
    float alpha = 0.f;
    if (FUSE_XT) alpha = 1.f - (float)tsel[n] * (1.f/128.f);

    float gs[NQ], gss[NQ], wsum = 0.f;
    #pragma unroll
    for (int q = 0; q < NQ; ++q) { gs[q]=0.f; gss[q]=0.f; }

    #pragma unroll
    for (int q = 0; q < NQ; ++q) {
        const int co = coh*32*NQ + q*32 + l31;
        const float bv = BtN[co];
        float wg = 0.f, fscv = 0.f, fbiv = 0.f;
        if (FUSE_XT) {
            wg   = wgw[co];
            fscv = fsc[n*COUT + co];
            fbiv = fbi[n*COUT + co];
        }
        float T0=0.f, T1=0.f, T2=0.f;
        if (TADD) {
            int yt = (y==0) ? 0 : (y==127 ? 2 : 1);
            const float* Tp = Tt + (size_t)(n*COUT + co)*9 + yt*3;
            T0 = Tp[0]; T1 = Tp[1]; T2 = Tp[2];
        }
        #pragma unroll
        for (int mt = 0; mt < 2; ++mt) {
            #pragma unroll
            for (int reg = 0; reg < 16; ++reg) {
                const int x = pxh*64 + mt*32 + (reg&3) + 8*(reg>>2) + 4*lhi;
                float v = acc[mt][q][reg] + bv;
                if (TADD) v += (x==0) ? T0 : (x==127 ? T2 : T1);
                if (FUSE_GN) { gs[q] += v; gss[q] += v*v; }
                if (FUSE_XT) {
                    float fv = __bfloat162float(featRow[(size_t)x*COUT + co]);
                    float yy = fv*fscv + fbiv;
                    float feat = yy * sigm(yy);
                    float xt = feat - alpha*v;
                    outRow[(size_t)x*COUT + co] = f2b(xt);
                    wsum += xt * wg;
                } else {
                    outRow[(size_t)x*COUT + co] = f2b(v);
                }
            }
        }
    }

    if (FUSE_GN) {
        constexpr int LG = (COUT==128) ? 4 : 3;   // log2(channels per group)
        #pragma unroll
        for (int q = 0; q < NQ; ++q) {
            float a = gs[q], b = gss[q];
            #pragma unroll
            for (int m = 1; m < (1<<LG); m <<= 1) { a += __shfl_xor(a, m); b += __shfl_xor(b, m); }
            a += __shfl_xor(a, 32); b += __shfl_xor(b, 32);
            if (lhi == 0 && (l31 & ((1<<LG)-1)) == 0) {
                int jp = (COUT==128) ? (q*2 + (l31>>4)) : (l31>>3);
                redS[wid][jp] = a; redSS[wid][jp] = b;
            }
        }
        __syncthreads();
        if (tid < 8) {
            int gg = tid;
            float S = 0.f, SS = 0.f;
            #pragma unroll
            for (int w = 0; w < 8; ++w) {
                if (((w>>1)&1) == (gg>>2)) { S += redS[w][gg&3]; SS += redSS[w][gg&3]; }
            }
            gpart[((size_t)(n*64 + tile))*16 + 2*gg]     = S;
            gpart[((size_t)(n*64 + tile))*16 + 2*gg + 1] = SS;
        }
    }
    if (FUSE_XT) {
        float a = wsum;
        #pragma unroll
        for (int m = 1; m < 64; m <<= 1) a += __shfl_xor(a, m);
        if (lane == 0) redW[wid] = a;
        __syncthreads();
        if (tid == 0) {
            float s = 0.f;
            #pragma unroll
            for (int w = 0; w < 8; ++w) s += redW[w];
            wpart[n*64 + tile] = s;
        }
    }
}

// ---------------------------------------------------------------------------
// Weight prep: gather per sample (experts), reorder [co][cin][3][3] fp32 ->
// Wt[n][r][co][cin] bf16 (zero-pad co >= COsrc), gather bias -> Bt[n][co].
// ---------------------------------------------------------------------------
__global__ void __launch_bounds__(256)
wtprep_kernel(const float* __restrict__ w, const float* __restrict__ b,
              const int* __restrict__ t, bf16* __restrict__ Wt, float* __restrict__ Bt,
              int CO, int COsrc, int CIN, int CINW, int gather)
{
    int idx = blockIdx.x*256 + threadIdx.x;
    int total = 8*9*CO*CIN;
    if (idx >= total) return;
    int cin = idx & (CIN-1);
    int tmp = idx / CIN;
    int co  = tmp % CO;
    int tmp2 = tmp / CO;
    int r   = tmp2 % 9;
    int n   = tmp2 / 9;
    int sel = gather ? t[n] : 0;
    float v = 0.f;
    if (co < COsrc) v = w[(((size_t)sel*COsrc + co)*CINW + cin)*9 + r];
    Wt[idx] = f2b(v);
    if (cin==0 && r==0) Bt[n*CO+co] = (co < COsrc) ? b[(size_t)sel*COsrc + co] : 0.f;
}

// ---------------------------------------------------------------------------
// Constant-channel table for c1.
// ---------------------------------------------------------------------------
__global__ void __launch_bounds__(256)
tprep_kernel(const int* __restrict__ t, const float* __restrict__ c1w,
             const float* __restrict__ tc, float* __restrict__ Tt)
{
    int idx = blockIdx.x*256 + threadIdx.x;
    if (idx >= 8*128) return;
    int n = idx >> 7, co = idx & 127;
    const float* wp = c1w + ((size_t)t[n]*128 + co)*129*9 + 128*9;
    float w9[9];
    #pragma unroll
    for (int i=0;i<9;++i) w9[i] = wp[i];
    float tcv = tc[n];
    #pragma unroll
    for (int yt=0; yt<3; ++yt)
        #pragma unroll
        for (int xt=0; xt<3; ++xt) {
            float s = 0.f;
            #pragma unroll
            for (int dy=0; dy<3; ++dy)
                #pragma unroll
                for (int dx=0; dx<3; ++dx) {
                    bool vy = (yt==0) ? (dy>=1) : ((yt==2) ? (dy<=1) : true);
                    bool vx = (xt==0) ? (dx>=1) : ((xt==2) ? (dx<=1) : true);
                    if (vy && vx) s += w9[dy*3+dx];
                }
            Tt[(size_t)idx*9 + yt*3+xt] = tcv*s;
        }
}

// ---------------------------------------------------------------------------
// fe1: direct 3x3 conv, Cin=3, NCHW fp32 in -> NHWC bf16 out (Cout=64), RAW.
// ---------------------------------------------------------------------------
__global__ void __launch_bounds__(256)
fe1_kernel(const float* __restrict__ in, const float* __restrict__ w,
           const float* __restrict__ bias, bf16* __restrict__ out)
{
    const int n   = blockIdx.z;
    const int co0 = blockIdx.y * 8;
    const int tx0 = (blockIdx.x & 7) * 16;
    const int ty0 = (blockIdx.x >> 3) * 16;
    const int lx = threadIdx.x & 15, ly = threadIdx.x >> 4;
    __shared__ float tileS[18][19];
    float acc[8];
    #pragma unroll
    for (int i=0;i<8;++i) acc[i] = bias[co0+i];
    const float* inN = in + (size_t)n*3*IMG;
    for (int ci=0; ci<3; ++ci) {
        __syncthreads();
        for (int idx = threadIdx.x; idx < 18*18; idx += 256) {
            int tyy = idx/18, txx = idx - tyy*18;
            int gy = ty0+tyy-1, gx = tx0+txx-1;
            float v = 0.f;
            if ((unsigned)gy < 128u && (unsigned)gx < 128u) v = inN[ci*IMG + gy*128+gx];
            tileS[tyy][txx] = v;
        }
        __syncthreads();
        float v[9];
        #pragma unroll
        for (int ky=0;ky<3;++ky)
            #pragma unroll
            for (int kx=0;kx<3;++kx) v[ky*3+kx] = tileS[ly+ky][lx+kx];
        #pragma unroll
        for (int c=0;c<8;++c) {
            const float* wp = w + ((co0+c)*3 + ci)*9;
            #pragma unroll
            for (int k=0;k<9;++k) acc[c] = fmaf(v[k], wp[k], acc[c]);
        }
    }
    int gy = ty0+ly, gx = tx0+lx;
    uint4 o; o.x = pk(acc[0],acc[1]); o.y = pk(acc[2],acc[3]);
    o.z = pk(acc[4],acc[5]); o.w = pk(acc[6],acc[7]);
    *(uint4*)(out + ((size_t)n*IMG + gy*128+gx)*64 + co0) = o;
}

// ---------------------------------------------------------------------------
// GroupNorm stats partials for fe1 raw output (64 chunks per sample).
// ---------------------------------------------------------------------------
template<int C>
__global__ void __launch_bounds__(256)
gn_stats_nhwc(const bf16* __restrict__ x, float* __restrict__ partials)
{
    constexpr int L2CPG = (C==128) ? 4 : 3;
    const int chunk = blockIdx.x, n = blockIdx.y;
    const int t = threadIdx.x;
    const uint4* pv = (const uint4*)(x + ((size_t)n*IMG + chunk*256 + t)*C);
    float s[8], ss[8];
    #pragma unroll
    for (int g=0; g<8; ++g) { s[g]=0.f; ss[g]=0.f; }
    #pragma unroll
    for (int v=0; v<C/8; ++v) {
        int g = (v*8) >> L2CPG;
        uint4 u = pv[v];
        float f0=blo(u.x), f1=bhi(u.x), f2=blo(u.y), f3=bhi(u.y);
        float f4=blo(u.z), f5=bhi(u.z), f6=blo(u.w), f7=bhi(u.w);
        s[g]  += ((f0+f1)+(f2+f3)) + ((f4+f5)+(f6+f7));
        ss[g] += ((f0*f0+f1*f1)+(f2*f2+f3*f3)) + ((f4*f4+f5*f5)+(f6*f6+f7*f7));
    }
    __shared__ float sh[16][256];
    #pragma unroll
    for (int g=0; g<8; ++g) { sh[2*g][t] = s[g]; sh[2*g+1][t] = ss[g]; }
    __syncthreads();
    for (int off=128; off>0; off>>=1) {
        if (t < off) {
            #pragma unroll
            for (int k=0;k<16;++k) sh[k][t] += sh[k][t+off];
        }
        __syncthreads();
    }
    if (t < 16) partials[((size_t)n*64 + chunk)*16 + t] = sh[t][0];
}

__global__ void __launch_bounds__(128)
gn_final(const float* __restrict__ partials, const float* __restrict__ scale,
         const float* __restrict__ bias, const int* __restrict__ tsel,
         int C, int l2cpg, float* __restrict__ scA, float* __restrict__ biA)
{
    int n = blockIdx.x, c = threadIdx.x;
    if (c >= C) return;
    int g = c >> l2cpg;
    float s=0.f, ss=0.f;
    for (int k=0;k<64;++k) {
        s  += partials[((size_t)n*64+k)*16 + 2*g];
        ss += partials[((size_t)n*64+k)*16 + 2*g + 1];
    }
    float cnt = (float)IMG * (float)(C>>3);
    float m = s/cnt, var = ss/cnt - m*m;
    float r = rsqrtf(var + EPSV);
    int po = tsel ? tsel[n]*C : 0;
    float sc = scale[po+c]*r;
    scA[n*C+c] = sc;
    biA[n*C+c] = bias[po+c] - m*sc;
}

// ---------------------------------------------------------------------------
// time embedding + expert MLP -> scalar tc[n]
// ---------------------------------------------------------------------------
__global__ void __launch_bounds__(256)
time_mlp_kernel(const int* __restrict__ t,
                const float* __restrict__ w1, const float* __restrict__ b1,
                const float* __restrict__ w2, const float* __restrict__ b2,
                float* __restrict__ tc)
{
    const int n = blockIdx.x;
    const int ti = t[n];
    const int tid = threadIdx.x;
    __shared__ float temb[256];
    __shared__ float h[256];
    {
        int j = tid & 127;
        float fr = expf(-9.210340371976184f / 127.f * (float)j);
        float e = (float)ti * fr;
        temb[tid] = (tid < 128) ? sinf(e) : cosf(e);
    }
    __syncthreads();
    {
        const float* w1p = w1 + ((size_t)ti * 256 + tid) * 256;
        float s = b1[(size_t)ti * 256 + tid];
        for (int j = 0; j < 256; ++j) s += w1p[j] * temb[j];
        h[tid] = s * sigm(s);
    }
    __syncthreads();
    float part = 0.f;
    if (tid < 128) {
        const float* w2p = w2 + ((size_t)ti * 128 + tid) * 256;
        float s = b2[(size_t)ti * 128 + tid];
        for (int j = 0; j < 256; ++j) s += w2p[j] * h[j];
        part = s;
    }
    __shared__ float red[256];
    red[tid] = part;
    __syncthreads();
    for (int off = 128; off > 0; off >>= 1) {
        if (tid < off) red[tid] += red[tid + off];
        __syncthreads();
    }
    if (tid == 0) tc[n] = red[0] * (1.f / 128.f);
}

// ---------------------------------------------------------------------------
// Final weight: reduce 64 per-tile pool partials per sample.
// ---------------------------------------------------------------------------
__global__ void __launch_bounds__(64)
weight_final_kernel(const float* __restrict__ wpart, const float* __restrict__ wg_b,
                    float* __restrict__ outw)
{
    const int n = blockIdx.x;
    float s = wpart[n*64 + threadIdx.x];
    #pragma unroll
    for (int m = 1; m < 64; m <<= 1) s += __shfl_xor(s, m);
    if (threadIdx.x == 0) outw[n] = sigm(s * (1.f/16384.f) + wg_b[0]);
}

// ---------------------------------------------------------------------------
// Extract channels 0..2 of padded cr2 output (NHWC64) -> NCHW fp32 + sigmoid.
// ---------------------------------------------------------------------------
__global__ void __launch_bounds__(256)
extract_kernel(const bf16* __restrict__ in, float* __restrict__ out)
{
    int n = blockIdx.y;
    int px = blockIdx.x*256 + threadIdx.x;
    const bf16* p = in + ((size_t)n*IMG + px)*64;
    float r0 = __bfloat162float(p[0]);
    float r1 = __bfloat162float(p[1]);
    float r2 = __bfloat162float(p[2]);
    size_t ob = (size_t)n*3*IMG + px;
    out[ob]         = sigm(r0);
    out[ob + IMG]   = sigm(r1);
    out[ob + 2*IMG] = sigm(r2);
}

// ---------------------------------------------------------------------------
extern "C" void kernel_launch(void* const* d_in, const int* in_sizes, int n_in,
                              void* d_out, int out_size, void* d_ws, size_t ws_size,
                              hipStream_t stream)
{
    (void)in_sizes; (void)n_in; (void)out_size; (void)ws_size;

    const float* x      = (const float*)d_in[0];
    const int*   t      = (const int*)  d_in[1];
    const float* fe_w1  = (const float*)d_in[2];
    const float* fe_b1  = (const float*)d_in[3];
    const float* fe_g1s = (const float*)d_in[4];
    const float* fe_g1b = (const float*)d_in[5];
    const float* fe_w2  = (const float*)d_in[6];
    const float* fe_b2  = (const float*)d_in[7];
    const float* fe_g2s = (const float*)d_in[8];
    const float* fe_g2b = (const float*)d_in[9];
    const float* mlp_w1 = (const float*)d_in[10];
    const float* mlp_b1 = (const float*)d_in[11];
    const float* mlp_w2 = (const float*)d_in[12];
    const float* mlp_b2 = (const float*)d_in[13];
    const float* c1w    = (const float*)d_in[14];
    const float* c1b    = (const float*)d_in[15];
    const float* g1s    = (const float*)d_in[16];
    const float* g1b    = (const float*)d_in[17];
    const float* c2w    = (const float*)d_in[18];
    const float* c2b    = (const float*)d_in[19];
    const float* g2s    = (const float*)d_in[20];
    const float* g2b    = (const float*)d_in[21];
    const float* c3w    = (const float*)d_in[22];
    const float* c3b    = (const float*)d_in[23];
    const float* cr_w1  = (const float*)d_in[24];
    const float* cr_b1  = (const float*)d_in[25];
    const float* cr_gs  = (const float*)d_in[26];
    const float* cr_gb  = (const float*)d_in[27];
    const float* cr_w2  = (const float*)d_in[28];
    const float* cr_b2  = (const float*)d_in[29];
    const float* wg_w   = (const float*)d_in[30];
    const float* wg_b   = (const float*)d_in[31];

    char* ws = (char*)d_ws;
    bf16* A   = (bf16*)(ws);                    // fe2 RAW out [8][IMG][128]
    bf16* Bb  = (bf16*)(ws + 33554432);
    bf16* Cb  = (bf16*)(ws + 67108864);
    bf16* Wt  = (bf16*)(ws + 100663296);        // <= 2359296 B
    float* Bt = (float*)(ws + 103022592);       // 4096 B
    float* Tt = (float*)(ws + 103026688);       // 36864 B
    float* tc = (float*)(ws + 103063552);       // 32 B
    bf16* zb  = (bf16*)(ws + 103063616);        // 64 B zero buffer
    float* gp = (float*)(ws + 103063680);       // gn partials 32768 B
    float* wp = (float*)(ws + 103096448);       // pool partials 2048 B
    // per-stage GN affine buffers (4KB each)
    float* scF1 = (float*)(ws + 103098496); float* biF1 = (float*)(ws + 103102592);
    float* scF2 = (float*)(ws + 103106688); float* biF2 = (float*)(ws + 103110784);
    float* scC1 = (float*)(ws + 103114880); float* biC1 = (float*)(ws + 103118976);
    float* scC2 = (float*)(ws + 103123072); float* biC2 = (float*)(ws + 103127168);
    float* scR1 = (float*)(ws + 103131264); float* biR1 = (float*)(ws + 103135360);

    float* out_img = (float*)d_out;             // [8,3,128,128] fp32
    float* out_w   = out_img + 393216;          // [8,1,1,1] fp32

    dim3 blk(256);
    dim3 cblk(512);
    dim3 cgrid(64, 1, 8);
    hipMemsetAsync(zb, 0, 64, stream);

    time_mlp_kernel<<<8, blk, 0, stream>>>(t, mlp_w1, mlp_b1, mlp_w2, mlp_b2, tc);
    tprep_kernel<<<4, blk, 0, stream>>>(t, c1w, tc, Tt);

    // fe1: x -> Bb RAW; stats -> scF1/biF1
    fe1_kernel<<<dim3(64, 8, 8), blk, 0, stream>>>(x, fe_w1, fe_b1, Bb);
    gn_stats_nhwc<64><<<dim3(64, 8), blk, 0, stream>>>(Bb, gp);
    gn_final<<<8, 128, 0, stream>>>(gp, fe_g1s, fe_g1b, nullptr, 64, 3, scF1, biF1);

    // fe2: gnsilu(Bb;F1) -> A RAW  [GN stats fused] -> scF2/biF2
    wtprep_kernel<<<2304, blk, 0, stream>>>(fe_w2, fe_b2, t, Wt, Bt, 128, 128, 64, 64, 0);
    mfma_conv3x3<64,128,false,true,true,false><<<cgrid, cblk, 0, stream>>>(
        Bb, Wt, Bt, A, nullptr, zb, gp, scF1, biF1, nullptr, nullptr, nullptr, nullptr, nullptr, nullptr);
    gn_final<<<8, 128, 0, stream>>>(gp, fe_g2s, fe_g2b, nullptr, 128, 4, scF2, biF2);

    // c1: gnsilu(A;F2) -> Bb RAW (gathered weights, +tc via Tt) -> scC1/biC1
    wtprep_kernel<<<4608, blk, 0, stream>>>(c1w, c1b, t, Wt, Bt, 128, 128, 128, 129, 1);
    mfma_conv3x3<128,128,true,true,true,false><<<cgrid, cblk, 0, stream>>>(
        A, Wt, Bt, Bb, Tt, zb, gp, scF2, biF2, nullptr, nullptr, nullptr, nullptr, nullptr, nullptr);
    gn_final<<<8, 128, 0, stream>>>(gp, g1s, g1b, t, 128, 4, scC1, biC1);

    // c2: gnsilu(Bb;C1) -> Cb RAW -> scC2/biC2
    wtprep_kernel<<<4608, blk, 0, stream>>>(c2w, c2b, t, Wt, Bt, 128, 128, 128, 128, 1);
    mfma_conv3x3<128,128,false,true,true,false><<<cgrid, cblk, 0, stream>>>(
        Bb, Wt, Bt, Cb, nullptr, zb, gp, scC1, biC1, nullptr, nullptr, nullptr, nullptr, nullptr, nullptr);
    gn_final<<<8, 128, 0, stream>>>(gp, g2s, g2b, t, 128, 4, scC2, biC2);

    // c3: gnsilu(Cb;C2) -> noise; x_t = silu(affine(A;F2)) - alpha*noise -> Bb
    wtprep_kernel<<<4608, blk, 0, stream>>>(c3w, c3b, t, Wt, Bt, 128, 128, 128, 128, 1);
    mfma_conv3x3<128,128,false,true,false,true><<<cgrid, cblk, 0, stream>>>(
        Cb, Wt, Bt, Bb, nullptr, zb, nullptr, scC2, biC2, A, scF2, biF2, t, wg_w, wp);
    weight_final_kernel<<<8, 64, 0, stream>>>(wp, wg_b, out_w);

    // cr1: Bb (x_t, final values; no GNIN) -> Cb RAW -> scR1/biR1
    wtprep_kernel<<<2304, blk, 0, stream>>>(cr_w1, cr_b1, t, Wt, Bt, 64, 64, 128, 128, 0);
    mfma_conv3x3<128,64,false,false,true,false><<<cgrid, cblk, 0, stream>>>(
        Bb, Wt, Bt, Cb, nullptr, zb, gp, nullptr, nullptr, nullptr, nullptr, nullptr, nullptr, nullptr, nullptr);
    gn_final<<<8, 128, 0, stream>>>(gp, cr_gs, cr_gb, nullptr, 64, 3, scR1, biR1);

    // cr2: gnsilu(Cb;R1) -> A (padded 64), then extract+sigmoid
    wtprep_kernel<<<1152, blk, 0, stream>>>(cr_w2, cr_b2, t, Wt, Bt, 64, 3, 64, 64, 0);
    mfma_conv3x3<64,64,false,true,false,false><<<cgrid, cblk, 0, stream>>>(
        Cb, Wt, Bt, A, nullptr, zb, nullptr, scR1, biR1, nullptr, nullptr, nullptr, nullptr, nullptr, nullptr);
    extract_kernel<<<dim3(64, 8), blk, 0, stream>>>(A, out_img);
}

// Round 12
// 354.252 us; speedup vs baseline: 1.2067x; 1.2067x over previous
//
#include <hip/hip_runtime.h>
#include <hip/hip_bf16.h>

typedef __hip_bfloat16 bf16;

#define HW 128
#define IMG 16384     // 128*128
#define EPSV 1e-5f

typedef __bf16 b16x8 __attribute__((ext_vector_type(8)));
typedef float f32x16 __attribute__((ext_vector_type(16)));

__device__ __forceinline__ float u2f(unsigned int u){ union{unsigned int i; float f;}c; c.i=u; return c.f; }
__device__ __forceinline__ float blo(unsigned int u){ return u2f(u<<16); }
__device__ __forceinline__ float bhi(unsigned int u){ return u2f(u & 0xffff0000u); }
__device__ __forceinline__ unsigned short f2bu(float v){ bf16 h=__float2bfloat16(v); union{bf16 b; unsigned short s;}c; c.b=h; return c.s; }
__device__ __forceinline__ unsigned int pk(float a, float b){ return (unsigned int)f2bu(a) | ((unsigned int)f2bu(b)<<16); }
__device__ __forceinline__ bf16 f2b(float v){ return __float2bfloat16(v); }
__device__ __forceinline__ float sigm(float x){ return 1.f/(1.f+__expf(-x)); }

__device__ __forceinline__ void gload16(const void* g, void* l) {
    __builtin_amdgcn_global_load_lds((const __attribute__((address_space(1))) unsigned int*)(g),
                                     (__attribute__((address_space(3))) unsigned int*)(l), 16, 0, 0);
}

__device__ __forceinline__ f32x16 MFMA(b16x8 a, b16x8 b, f32x16 c){
    return __builtin_amdgcn_mfma_f32_32x32x16_bf16(a, b, c, 0, 0, 0);
}

// ---------------------------------------------------------------------------
// MFMA implicit-GEMM 3x3 conv, SAME padding — 8-wave high-occupancy (R10).
// Block 512 thr (8 waves): wave = 2 M-frags x 2 N-frags (64px x 64co),
// acc = 64 regs -> 4 waves/SIMD. Grid (64,1,8); tile = 2 rows x 128 px x COUT.
// X slab (2 rows + halo, 64 cin) staged via global_load_lds (swizzled src);
// W slice [COUT][64cin] double-buffered, staged during MFMA of prev phase.
// TADD: add constant-channel table Tt[n][co][3][3] (c1).
// FUSE_GN: emit per-(n,tile) GroupNorm partials (8 groups x {sum,sumsq}).
// FUSE_XT: out = feat - alpha*conv; emit per-(n,tile) wg-pool partials.
// OUT3: final conv — write sigmoid(v) for co<3 as NCHW fp32 to out3 only.
// ---------------------------------------------------------------------------
template<int CIN, int COUT, bool TADD, bool FUSE_GN, bool FUSE_XT, bool OUT3>
__global__ void __launch_bounds__(512, 4)
mfma_conv3x3(const bf16* __restrict__ act,
             const bf16* __restrict__ Wt,
             const float* __restrict__ Bt,
             bf16* __restrict__ outp,
             const float* __restrict__ Tt,
             const bf16* __restrict__ zerobuf,
             float* __restrict__ gpart,
             const bf16* __restrict__ featA,
             const int* __restrict__ tsel,
             const float* __restrict__ wgw,
             float* __restrict__ wpart,
             float* __restrict__ out3)
{
    static_assert(CIN==64 || CIN==128, "");
    static_assert(COUT==64 || COUT==128, "");
    constexpr int NQ  = COUT/64;      // n-frags per wave (co-half has NQ*32 co)
    constexpr int CH  = CIN/64;       // cin chunks
    constexpr int P   = 9*CH;         // phases
    constexpr int WCH = COUT/8;       // weight chunks (1KB each)
    constexpr int WSZ = WCH*1024;

    __shared__ char Xb[33792];        // 264 slots x 128B (260 used: 2 rows x 130 x')
    __shared__ char Wa[2][WSZ];
    __shared__ float redS[8][4], redSS[8][4], redW[8];

    const int n    = blockIdx.z;
    const int tile = blockIdx.x;
    const int y0   = tile*2;
    const int tid  = threadIdx.x;
    const int lane = tid & 63;
    const int wid  = tid >> 6;        // 0..7
    const int row  = wid >> 2;        // image row within tile (0/1)
    const int coh  = (wid >> 1) & 1;  // co half
    const int pxh  = wid & 1;         // px half (x offset 0 / 64)
    const int l31  = lane & 31;
    const int lhi  = lane >> 5;
    const int g    = lane & 7;

    const bf16* actN = act + (size_t)n * IMG * CIN;
    const bf16* WtN  = Wt  + (size_t)n * 9 * COUT * CIN;

    f32x16 acc[2][NQ];
    #pragma unroll
    for (int i=0;i<2;++i)
        #pragma unroll
        for (int j=0;j<NQ;++j)
            #pragma unroll
            for (int k=0;k<16;++k) acc[i][j][k] = 0.f;

    // ---- staging helpers ----
    auto stage_X = [&](int dy, int ch) {
        const int ry0 = y0 + dy - 1;
        for (int u = wid; u < 33; u += 8) {
            int s = u*8 + (lane>>3);         // slot index
            int r  = (s >= 130) ? 1 : 0;
            int xp = s - r*130;
            int xx = xp - 1;
            int ry = ry0 + r;
            const void* src = zerobuf;
            if (s < 260 && (unsigned)xx < 128u && (unsigned)ry < 128u)
                src = actN + ((size_t)(ry*128 + xx)*CIN + ch*64 + 8*(g ^ (s&7)));
            gload16(src, Xb + u*1024);
        }
    };
    auto stage_W = [&](int r, int ch, int buf) {
        for (int u = wid; u < WCH; u += 8) {
            int co = u*8 + (lane>>3);
            const void* src = WtN + ((size_t)(r*COUT + co)*CIN + ch*64 + 8*(g ^ (co&7)));
            gload16(src, Wa[buf] + u*1024);
        }
    };

    // ---- prologue ----
    stage_X(0, 0);
    stage_W(0, 0, 0);
    __syncthreads();

    int buf = 0;
    for (int p = 0; p < P; ++p) {
        const int dx = p % 3;
        const bool last = (p+1 == P);

        if (!last) {
            const int pn  = p + 1;
            const int ndx = pn % 3;
            const int npc = pn / 3;
            stage_W((npc/CH)*3 + ndx, npc % CH, buf ^ 1);
        }

        __builtin_amdgcn_s_setprio(1);
        #pragma unroll
        for (int s4 = 0; s4 < 4; ++s4) {
            const int koff = s4*32 + lhi*16;
            b16x8 bfr[NQ];
            #pragma unroll
            for (int q = 0; q < NQ; ++q) {
                int co = coh*32*NQ + q*32 + l31;
                bfr[q] = *(const b16x8*)(Wa[buf] + co*128 + (koff ^ ((co&7)<<4)));
            }
            b16x8 afr[2];
            #pragma unroll
            for (int mt = 0; mt < 2; ++mt) {
                int sl = row*130 + (pxh*2+mt)*32 + l31 + dx;
                afr[mt] = *(const b16x8*)(Xb + sl*128 + (koff ^ ((sl&7)<<4)));
            }
            #pragma unroll
            for (int mt = 0; mt < 2; ++mt)
                #pragma unroll
                for (int q = 0; q < NQ; ++q)
                    acc[mt][q] = MFMA(afr[mt], bfr[q], acc[mt][q]);
        }
        __builtin_amdgcn_s_setprio(0);

        if (!last) {
            if (dx == 2) {
                __syncthreads();
                const int npc = (p + 1) / 3;
                stage_X(npc / CH, npc % CH);
                __syncthreads();
            } else {
                __syncthreads();
            }
        }
        buf ^= 1;
    }

    // ---- epilogue ----
    const float* BtN = Bt + n*COUT;
    const int y = y0 + row;
    bf16* outRow = outp + ((size_t)n*IMG + (size_t)y*128)*COUT;
    const bf16* featRow = FUSE_XT ? (featA + ((size_t)n*IMG + (size_t)y*128)*COUT) : nullptr;
    float alpha = 0.f;
    if (FUSE_XT) alpha = 1.f - (float)tsel[n] * (1.f/128.f);

    float gs[NQ], gss[NQ], wsum = 0.f;
    #pragma unroll
    for (int q = 0; q < NQ; ++q) { gs[q]=0.f; gss[q]=0.f; }

    #pragma unroll
    for (int q = 0; q < NQ; ++q) {
        const int co = coh*32*NQ + q*32 + l31;
        const float bv = BtN[co];
        float wg = 0.f;
        if (FUSE_XT) wg = wgw[co];
        float T0=0.f, T1=0.f, T2=0.f;
        if (TADD) {
            int yt = (y==0) ? 0 : (y==127 ? 2 : 1);
            const float* Tp = Tt + (size_t)(n*COUT + co)*9 + yt*3;
            T0 = Tp[0]; T1 = Tp[1]; T2 = Tp[2];
        }
        #pragma unroll
        for (int mt = 0; mt < 2; ++mt) {
            #pragma unroll
            for (int reg = 0; reg < 16; ++reg) {
                const int x = pxh*64 + mt*32 + (reg&3) + 8*(reg>>2) + 4*lhi;
                float v = acc[mt][q][reg] + bv;
                if (TADD) v += (x==0) ? T0 : (x==127 ? T2 : T1);
                if (FUSE_GN) { gs[q] += v; gss[q] += v*v; }
                if (OUT3) {
                    if (co < 3)
                        out3[((size_t)n*3 + co)*IMG + (size_t)y*128 + x] = sigm(v);
                } else if (FUSE_XT) {
                    float fv = __bfloat162float(featRow[(size_t)x*COUT + co]);
                    float xt = fv - alpha*v;
                    outRow[(size_t)x*COUT + co] = f2b(xt);
                    wsum += xt * wg;
                } else {
                    outRow[(size_t)x*COUT + co] = f2b(v);
                }
            }
        }
    }

    if (FUSE_GN) {
        constexpr int LG = (COUT==128) ? 4 : 3;   // log2(channels per group)
        #pragma unroll
        for (int q = 0; q < NQ; ++q) {
            float a = gs[q], b = gss[q];
            #pragma unroll
            for (int m = 1; m < (1<<LG); m <<= 1) { a += __shfl_xor(a, m); b += __shfl_xor(b, m); }
            a += __shfl_xor(a, 32); b += __shfl_xor(b, 32);
            if (lhi == 0 && (l31 & ((1<<LG)-1)) == 0) {
                int jp = (COUT==128) ? (q*2 + (l31>>4)) : (l31>>3);
                redS[wid][jp] = a; redSS[wid][jp] = b;
            }
        }
        __syncthreads();
        if (tid < 8) {
            int gg = tid;
            float S = 0.f, SS = 0.f;
            #pragma unroll
            for (int w = 0; w < 8; ++w) {
                if (((w>>1)&1) == (gg>>2)) { S += redS[w][gg&3]; SS += redSS[w][gg&3]; }
            }
            gpart[((size_t)(n*64 + tile))*16 + 2*gg]     = S;
            gpart[((size_t)(n*64 + tile))*16 + 2*gg + 1] = SS;
        }
    }
    if (FUSE_XT) {
        float a = wsum;
        #pragma unroll
        for (int m = 1; m < 64; m <<= 1) a += __shfl_xor(a, m);
        if (lane == 0) redW[wid] = a;
        __syncthreads();
        if (tid == 0) {
            float s = 0.f;
            #pragma unroll
            for (int w = 0; w < 8; ++w) s += redW[w];
            wpart[n*64 + tile] = s;
        }
    }
}

// ---------------------------------------------------------------------------
// Weight prep: gather per sample (experts), reorder [co][cin][3][3] fp32 ->
// Wt[n][r][co][cin] bf16 (zero-pad co >= COsrc), gather bias -> Bt[n][co].
// ---------------------------------------------------------------------------
__global__ void __launch_bounds__(256)
wtprep_kernel(const float* __restrict__ w, const float* __restrict__ b,
              const int* __restrict__ t, bf16* __restrict__ Wt, float* __restrict__ Bt,
              int CO, int COsrc, int CIN, int CINW, int gather)
{
    int idx = blockIdx.x*256 + threadIdx.x;
    int total = 8*9*CO*CIN;
    if (idx >= total) return;
    int cin = idx & (CIN-1);
    int tmp = idx / CIN;
    int co  = tmp % CO;
    int tmp2 = tmp / CO;
    int r   = tmp2 % 9;
    int n   = tmp2 / 9;
    int sel = gather ? t[n] : 0;
    float v = 0.f;
    if (co < COsrc) v = w[(((size_t)sel*COsrc + co)*CINW + cin)*9 + r];
    Wt[idx] = f2b(v);
    if (cin==0 && r==0) Bt[n*CO+co] = (co < COsrc) ? b[(size_t)sel*COsrc + co] : 0.f;
}

// ---------------------------------------------------------------------------
// Constant-channel table for c1.
// ---------------------------------------------------------------------------
__global__ void __launch_bounds__(256)
tprep_kernel(const int* __restrict__ t, const float* __restrict__ c1w,
             const float* __restrict__ tc, float* __restrict__ Tt)
{
    int idx = blockIdx.x*256 + threadIdx.x;
    if (idx >= 8*128) return;
    int n = idx >> 7, co = idx & 127;
    const float* wp = c1w + ((size_t)t[n]*128 + co)*129*9 + 128*9;
    float w9[9];
    #pragma unroll
    for (int i=0;i<9;++i) w9[i] = wp[i];
    float tcv = tc[n];
    #pragma unroll
    for (int yt=0; yt<3; ++yt)
        #pragma unroll
        for (int xt=0; xt<3; ++xt) {
            float s = 0.f;
            #pragma unroll
            for (int dy=0; dy<3; ++dy)
                #pragma unroll
                for (int dx=0; dx<3; ++dx) {
                    bool vy = (yt==0) ? (dy>=1) : ((yt==2) ? (dy<=1) : true);
                    bool vx = (xt==0) ? (dx>=1) : ((xt==2) ? (dx<=1) : true);
                    if (vy && vx) s += w9[dy*3+dx];
                }
            Tt[(size_t)idx*9 + yt*3+xt] = tcv*s;
        }
}

// ---------------------------------------------------------------------------
// fe1: direct 3x3 conv, Cin=3, NCHW fp32 in -> NHWC bf16 out (Cout=64),
// with FUSED GroupNorm partials: block (chunk, co-octet=GN-group, n) reduces
// its 16x16x8 outputs to (sum, sumsq) -> gpart[(n*64+chunk)*16 + 2g].
// ---------------------------------------------------------------------------
__global__ void __launch_bounds__(256)
fe1_kernel(const float* __restrict__ in, const float* __restrict__ w,
           const float* __restrict__ bias, bf16* __restrict__ out,
           float* __restrict__ gpart)
{
    const int n   = blockIdx.z;
    const int co0 = blockIdx.y * 8;
    const int tx0 = (blockIdx.x & 7) * 16;
    const int ty0 = (blockIdx.x >> 3) * 16;
    const int lx = threadIdx.x & 15, ly = threadIdx.x >> 4;
    __shared__ float tileS[18][19];
    float acc[8];
    #pragma unroll
    for (int i=0;i<8;++i) acc[i] = bias[co0+i];
    const float* inN = in + (size_t)n*3*IMG;
    for (int ci=0; ci<3; ++ci) {
        __syncthreads();
        for (int idx = threadIdx.x; idx < 18*18; idx += 256) {
            int tyy = idx/18, txx = idx - tyy*18;
            int gy = ty0+tyy-1, gx = tx0+txx-1;
            float v = 0.f;
            if ((unsigned)gy < 128u && (unsigned)gx < 128u) v = inN[ci*IMG + gy*128+gx];
            tileS[tyy][txx] = v;
        }
        __syncthreads();
        float v[9];
        #pragma unroll
        for (int ky=0;ky<3;++ky)
            #pragma unroll
            for (int kx=0;kx<3;++kx) v[ky*3+kx] = tileS[ly+ky][lx+kx];
        #pragma unroll
        for (int c=0;c<8;++c) {
            const float* wp = w + ((co0+c)*3 + ci)*9;
            #pragma unroll
            for (int k=0;k<9;++k) acc[c] = fmaf(v[k], wp[k], acc[c]);
        }
    }
    int gy = ty0+ly, gx = tx0+lx;
    uint4 o; o.x = pk(acc[0],acc[1]); o.y = pk(acc[2],acc[3]);
    o.z = pk(acc[4],acc[5]); o.w = pk(acc[6],acc[7]);
    *(uint4*)(out + ((size_t)n*IMG + gy*128+gx)*64 + co0) = o;

    // fused GN partials (this block covers one GN group g = blockIdx.y)
    float s = 0.f, ss = 0.f;
    #pragma unroll
    for (int c=0;c<8;++c) { s += acc[c]; ss += acc[c]*acc[c]; }
    __shared__ float sh2[2][256];
    __syncthreads();
    sh2[0][threadIdx.x] = s; sh2[1][threadIdx.x] = ss;
    __syncthreads();
    for (int off=128; off>0; off>>=1) {
        if ((int)threadIdx.x < off) {
            sh2[0][threadIdx.x] += sh2[0][threadIdx.x+off];
            sh2[1][threadIdx.x] += sh2[1][threadIdx.x+off];
        }
        __syncthreads();
    }
    if (threadIdx.x == 0) {
        int chunk = blockIdx.x, g = blockIdx.y;
        gpart[((size_t)(n*64 + chunk))*16 + 2*g]     = sh2[0][0];
        gpart[((size_t)(n*64 + chunk))*16 + 2*g + 1] = sh2[1][0];
    }
}

__global__ void __launch_bounds__(128)
gn_final(const float* __restrict__ partials, const float* __restrict__ scale,
         const float* __restrict__ bias, const int* __restrict__ tsel,
         int C, int l2cpg, float* __restrict__ scA, float* __restrict__ biA)
{
    int n = blockIdx.x, c = threadIdx.x;
    if (c >= C) return;
    int g = c >> l2cpg;
    float s=0.f, ss=0.f;
    for (int k=0;k<64;++k) {
        s  += partials[((size_t)n*64+k)*16 + 2*g];
        ss += partials[((size_t)n*64+k)*16 + 2*g + 1];
    }
    float cnt = (float)IMG * (float)(C>>3);
    float m = s/cnt, var = ss/cnt - m*m;
    float r = rsqrtf(var + EPSV);
    int po = tsel ? tsel[n]*C : 0;
    float sc = scale[po+c]*r;
    scA[n*C+c] = sc;
    biA[n*C+c] = bias[po+c] - m*sc;
}

template<int C>
__global__ void __launch_bounds__(256)
gn_apply_nhwc(bf16* __restrict__ x, const float* __restrict__ scA, const float* __restrict__ biA)
{
    size_t e0 = ((size_t)blockIdx.x*256 + threadIdx.x)*8;
    int n = (int)(e0 >> ((C==128) ? 21 : 20));
    int c0 = (int)(e0 & (C-1));
    const float4 sA = *(const float4*)(scA + n*C + c0);
    const float4 sB = *(const float4*)(scA + n*C + c0 + 4);
    const float4 bA = *(const float4*)(biA + n*C + c0);
    const float4 bB = *(const float4*)(biA + n*C + c0 + 4);
    uint4* p = (uint4*)(x + e0);
    uint4 u = *p;
    float f[8] = {blo(u.x),bhi(u.x),blo(u.y),bhi(u.y),blo(u.z),bhi(u.z),blo(u.w),bhi(u.w)};
    f[0]=f[0]*sA.x+bA.x; f[1]=f[1]*sA.y+bA.y; f[2]=f[2]*sA.z+bA.z; f[3]=f[3]*sA.w+bA.w;
    f[4]=f[4]*sB.x+bB.x; f[5]=f[5]*sB.y+bB.y; f[6]=f[6]*sB.z+bB.z; f[7]=f[7]*sB.w+bB.w;
    #pragma unroll
    for (int i=0;i<8;++i) f[i] = f[i]*sigm(f[i]);
    u.x = pk(f[0],f[1]); u.y = pk(f[2],f[3]); u.z = pk(f[4],f[5]); u.w = pk(f[6],f[7]);
    *p = u;
}

// ---------------------------------------------------------------------------
// time embedding + expert MLP -> scalar tc[n]
// ---------------------------------------------------------------------------
__global__ void __launch_bounds__(256)
time_mlp_kernel(const int* __restrict__ t,
                const float* __restrict__ w1, const float* __restrict__ b1,
                const float* __restrict__ w2, const float* __restrict__ b2,
                float* __restrict__ tc)
{
    const int n = blockIdx.x;
    const int ti = t[n];
    const int tid = threadIdx.x;
    __shared__ float temb[256];
    __shared__ float h[256];
    {
        int j = tid & 127;
        float fr = expf(-9.210340371976184f / 127.f * (float)j);
        float e = (float)ti * fr;
        temb[tid] = (tid < 128) ? sinf(e) : cosf(e);
    }
    __syncthreads();
    {
        const float* w1p = w1 + ((size_t)ti * 256 + tid) * 256;
        float s = b1[(size_t)ti * 256 + tid];
        for (int j = 0; j < 256; ++j) s += w1p[j] * temb[j];
        h[tid] = s * sigm(s);
    }
    __syncthreads();
    float part = 0.f;
    if (tid < 128) {
        const float* w2p = w2 + ((size_t)ti * 128 + tid) * 256;
        float s = b2[(size_t)ti * 128 + tid];
        for (int j = 0; j < 256; ++j) s += w2p[j] * h[j];
        part = s;
    }
    __shared__ float red[256];
    red[tid] = part;
    __syncthreads();
    for (int off = 128; off > 0; off >>= 1) {
        if (tid < off) red[tid] += red[tid + off];
        __syncthreads();
    }
    if (tid == 0) tc[n] = red[0] * (1.f / 128.f);
}

// ---------------------------------------------------------------------------
// Final weight: reduce 64 per-tile pool partials per sample.
// ---------------------------------------------------------------------------
__global__ void __launch_bounds__(64)
weight_final_kernel(const float* __restrict__ wpart, const float* __restrict__ wg_b,
                    float* __restrict__ outw)
{
    const int n = blockIdx.x;
    float s = wpart[n*64 + threadIdx.x];
    #pragma unroll
    for (int m = 1; m < 64; m <<= 1) s += __shfl_xor(s, m);
    if (threadIdx.x == 0) outw[n] = sigm(s * (1.f/16384.f) + wg_b[0]);
}

// ---------------------------------------------------------------------------
extern "C" void kernel_launch(void* const* d_in, const int* in_sizes, int n_in,
                              void* d_out, int out_size, void* d_ws, size_t ws_size,
                              hipStream_t stream)
{
    (void)in_sizes; (void)n_in; (void)out_size; (void)ws_size;

    const float* x      = (const float*)d_in[0];
    const int*   t      = (const int*)  d_in[1];
    const float* fe_w1  = (const float*)d_in[2];
    const float* fe_b1  = (const float*)d_in[3];
    const float* fe_g1s = (const float*)d_in[4];
    const float* fe_g1b = (const float*)d_in[5];
    const float* fe_w2  = (const float*)d_in[6];
    const float* fe_b2  = (const float*)d_in[7];
    const float* fe_g2s = (const float*)d_in[8];
    const float* fe_g2b = (const float*)d_in[9];
    const float* mlp_w1 = (const float*)d_in[10];
    const float* mlp_b1 = (const float*)d_in[11];
    const float* mlp_w2 = (const float*)d_in[12];
    const float* mlp_b2 = (const float*)d_in[13];
    const float* c1w    = (const float*)d_in[14];
    const float* c1b    = (const float*)d_in[15];
    const float* g1s    = (const float*)d_in[16];
    const float* g1b    = (const float*)d_in[17];
    const float* c2w    = (const float*)d_in[18];
    const float* c2b    = (const float*)d_in[19];
    const float* g2s    = (const float*)d_in[20];
    const float* g2b    = (const float*)d_in[21];
    const float* c3w    = (const float*)d_in[22];
    const float* c3b    = (const float*)d_in[23];
    const float* cr_w1  = (const float*)d_in[24];
    const float* cr_b1  = (const float*)d_in[25];
    const float* cr_gs  = (const float*)d_in[26];
    const float* cr_gb  = (const float*)d_in[27];
    const float* cr_w2  = (const float*)d_in[28];
    const float* cr_b2  = (const float*)d_in[29];
    const float* wg_w   = (const float*)d_in[30];
    const float* wg_b   = (const float*)d_in[31];

    char* ws = (char*)d_ws;
    bf16* A   = (bf16*)(ws);                    // [8][IMG][128] bf16
    bf16* Bb  = (bf16*)(ws + 33554432);
    bf16* Cb  = (bf16*)(ws + 67108864);
    bf16* Wt  = (bf16*)(ws + 100663296);        // <= 2359296 B
    float* Bt = (float*)(ws + 103022592);       // 4096 B
    float* Tt = (float*)(ws + 103026688);       // 36864 B
    float* tc = (float*)(ws + 103063552);       // 32 B
    bf16* zb  = (bf16*)(ws + 103063616);        // 64 B zero buffer
    float* gp = (float*)(ws + 103063680);       // gn partials 32768 B
    float* scA = (float*)(ws + 103096448);      // 4096 B
    float* biA = (float*)(ws + 103100544);      // 4096 B
    float* wp  = (float*)(ws + 103104640);      // pool partials 2048 B

    float* out_img = (float*)d_out;             // [8,3,128,128] fp32
    float* out_w   = out_img + 393216;          // [8,1,1,1] fp32

    dim3 blk(256);
    dim3 cblk(512);
    dim3 cgrid(64, 1, 8);
    hipMemsetAsync(zb, 0, 64, stream);

    time_mlp_kernel<<<8, blk, 0, stream>>>(t, mlp_w1, mlp_b1, mlp_w2, mlp_b2, tc);
    tprep_kernel<<<4, blk, 0, stream>>>(t, c1w, tc, Tt);

    // fe1: x -> Bb (NHWC 64) with fused GN partials
    fe1_kernel<<<dim3(64, 8, 8), blk, 0, stream>>>(x, fe_w1, fe_b1, Bb, gp);
    gn_final<<<8, 128, 0, stream>>>(gp, fe_g1s, fe_g1b, nullptr, 64, 3, scA, biA);
    gn_apply_nhwc<64><<<4096, blk, 0, stream>>>(Bb, scA, biA);

    // fe2: Bb(64) -> A(128)  [GN fused stats]
    wtprep_kernel<<<2304, blk, 0, stream>>>(fe_w2, fe_b2, t, Wt, Bt, 128, 128, 64, 64, 0);
    mfma_conv3x3<64,128,false,true,false,false><<<cgrid, cblk, 0, stream>>>(
        Bb, Wt, Bt, A, nullptr, zb, gp, nullptr, nullptr, nullptr, nullptr, nullptr);
    gn_final<<<8, 128, 0, stream>>>(gp, fe_g2s, fe_g2b, nullptr, 128, 4, scA, biA);
    gn_apply_nhwc<128><<<8192, blk, 0, stream>>>(A, scA, biA);
    // A = feat

    // c1: A -> Bb (gathered weights, +tc channel)  [GN fused stats]
    wtprep_kernel<<<4608, blk, 0, stream>>>(c1w, c1b, t, Wt, Bt, 128, 128, 128, 129, 1);
    mfma_conv3x3<128,128,true,true,false,false><<<cgrid, cblk, 0, stream>>>(
        A, Wt, Bt, Bb, Tt, zb, gp, nullptr, nullptr, nullptr, nullptr, nullptr);
    gn_final<<<8, 128, 0, stream>>>(gp, g1s, g1b, t, 128, 4, scA, biA);
    gn_apply_nhwc<128><<<8192, blk, 0, stream>>>(Bb, scA, biA);

    // c2: Bb -> Cb  [GN fused stats]
    wtprep_kernel<<<4608, blk, 0, stream>>>(c2w, c2b, t, Wt, Bt, 128, 128, 128, 128, 1);
    mfma_conv3x3<128,128,false,true,false,false><<<cgrid, cblk, 0, stream>>>(
        Bb, Wt, Bt, Cb, nullptr, zb, gp, nullptr, nullptr, nullptr, nullptr, nullptr);
    gn_final<<<8, 128, 0, stream>>>(gp, g2s, g2b, t, 128, 4, scA, biA);
    gn_apply_nhwc<128><<<8192, blk, 0, stream>>>(Cb, scA, biA);

    // c3: Cb -> Bb = x_t  [XT fused: x_t = feat(A) - alpha*noise + pooling]
    wtprep_kernel<<<4608, blk, 0, stream>>>(c3w, c3b, t, Wt, Bt, 128, 128, 128, 128, 1);
    mfma_conv3x3<128,128,false,false,true,false><<<cgrid, cblk, 0, stream>>>(
        Cb, Wt, Bt, Bb, nullptr, zb, nullptr, A, t, wg_w, wp, nullptr);
    weight_final_kernel<<<8, 64, 0, stream>>>(wp, wg_b, out_w);

    // cr1: Bb(x_t,128) -> Cb(64)  [GN fused stats]
    wtprep_kernel<<<2304, blk, 0, stream>>>(cr_w1, cr_b1, t, Wt, Bt, 64, 64, 128, 128, 0);
    mfma_conv3x3<128,64,false,true,false,false><<<cgrid, cblk, 0, stream>>>(
        Bb, Wt, Bt, Cb, nullptr, zb, gp, nullptr, nullptr, nullptr, nullptr, nullptr);
    gn_final<<<8, 128, 0, stream>>>(gp, cr_gs, cr_gb, nullptr, 64, 3, scA, biA);
    gn_apply_nhwc<64><<<4096, blk, 0, stream>>>(Cb, scA, biA);

    // cr2: Cb(64) -> out_img directly (sigmoid, NCHW fp32, co<3)
    wtprep_kernel<<<1152, blk, 0, stream>>>(cr_w2, cr_b2, t, Wt, Bt, 64, 3, 64, 64, 0);
    mfma_conv3x3<64,64,false,false,false,true><<<cgrid, cblk, 0, stream>>>(
        Cb, Wt, Bt, A, nullptr, zb, nullptr, nullptr, nullptr, nullptr, nullptr, out_img);
}